// Round 13
// baseline (410.367 us; speedup 1.0000x reference)
//
#include <hip/hip_runtime.h>
#include <hip/hip_fp16.h>

typedef _Float16 f16;
typedef _Float16 f16x4 __attribute__((ext_vector_type(4)));
typedef _Float16 f16x8 __attribute__((ext_vector_type(8)));
typedef float f32x4 __attribute__((ext_vector_type(4)));

#define B_SZ   4096
#define T_SZ   32
#define VOCAB  10000
#define E_SZ   300
#define H_SZ   300
#define KP     320          // embT row width (10x32)
#define GP     304          // per-gate padded N (19x16)
#define G4     1216         // 4*GP
#define LDA    328          // hbuf row stride f16
#define LDG    1224         // kR8 gates row stride f16
#define LDC    308          // cbuf row stride f32
#define XST    1224         // kX2 LDS out row stride f16 (bank spread)
#define ROWS   16
#define NBLK   (B_SZ/ROWS)  // 256 blocks -> 1 per CU

__device__ __forceinline__ float sigmoid_f(float x) {
    return 1.f / (1.f + __expf(-x));
}
__device__ __forceinline__ float tanh_f(float x) {
    return 2.f / (1.f + __expf(-2.f * x)) - 1.f;
}

// P0: embed_w f32 [V][300] -> embT f16 [V][320] zero-padded
__global__ void kP0(const float* __restrict__ ew, f16* __restrict__ embT) {
    int v = blockIdx.x, k = threadIdx.x;           // 320 threads
    embT[(size_t)v * KP + k] = (k < E_SZ) ? (f16)ew[(size_t)v * E_SZ + k] : (f16)0.f;
}

// kPW2: fused-stream packing (for kX2 / kR8): block (gate,nt,k20), 1 KB each.
__global__ void kPW2(const float* __restrict__ wih, const float* __restrict__ whh,
                     const float* __restrict__ bih, const float* __restrict__ bhh,
                     f16* __restrict__ Wpk, float* __restrict__ biasp) {
    int bid = blockIdx.x;                          // 0..1519 = (gate*19+nt)*20+k
    int lane = threadIdx.x;                        // 64
    int k = bid % 20, ntg = bid / 20;
    int nt = ntg % 19, gate = ntg / 19;
    int c = lane & 15, q = lane >> 4;
    int j = nt * 16 + c;
    int src = gate * H_SZ + j;
    f16 vals[8];
#pragma unroll
    for (int jj = 0; jj < 8; ++jj) {
        int kk = k * 32 + q * 8 + jj;
        float v = 0.f;
        if (j < H_SZ) {
            if (kk < KP) { if (kk < H_SZ) v = whh[(size_t)src * H_SZ + kk]; }
            else { int kx = kk - KP; if (kx < E_SZ) v = wih[(size_t)src * E_SZ + kx]; }
        }
        vals[jj] = (f16)v;
    }
    *(f16x8*)(Wpk + ((size_t)bid * 64 + lane) * 8) = *(const f16x8*)vals;
    if (k == 0 && q == 0)
        biasp[gate * GP + j] = (j < H_SZ) ? (bih[src] + bhh[src]) : 0.f;
}

// kPW4: gate-major W_hh-only packing: block (nt, gate, k10), 1 KB each.
// 800 blocks (760 real + 40 zero slack).
__global__ void kPW4(const float* __restrict__ whh, f16* __restrict__ WgS) {
    int bid = blockIdx.x;                          // 0..799
    int lane = threadIdx.x;
    int c = lane & 15, q = lane >> 4;
    f16 vals[8];
    if (bid < 760) {
        int nt = bid / 40, g = (bid % 40) / 10, k = bid % 10;
        int j = nt * 16 + c;
        int src = g * H_SZ + j;
#pragma unroll
        for (int jj = 0; jj < 8; ++jj) {
            int kk = k * 32 + q * 8 + jj;
            float v = (j < H_SZ && kk < H_SZ) ? whh[(size_t)src * H_SZ + kk] : 0.f;
            vals[jj] = (f16)v;
        }
    } else {
#pragma unroll
        for (int jj = 0; jj < 8; ++jj) vals[jj] = (f16)0.f;
    }
    *(f16x8*)(WgS + ((size_t)bid * 64 + lane) * 8) = *(const f16x8*)vals;
}

// P2: weight-normed classifier W = g * v / ||v||  -> Wc f32 [2][GP]
// cols 300..303 zeroed (fused classifier multiplies h(=0) by Wc there).
__global__ void kP2(const float* __restrict__ cls_v, const float* __restrict__ cls_g,
                    float* __restrict__ Wc) {
    int lane = threadIdx.x;
    for (int cl = 0; cl < 2; ++cl) {
        float s = 0.f;
        for (int j = lane; j < H_SZ; j += 64) { float v = cls_v[cl * H_SZ + j]; s += v * v; }
        for (int off = 32; off; off >>= 1) s += __shfl_down(s, off);
        float nrm = sqrtf(__shfl(s, 0));
        float scale = cls_g[cl] / nrm;
        for (int j = lane; j < GP; j += 64)
            Wc[cl * GP + j] = (j < H_SZ) ? cls_v[cl * H_SZ + j] * scale : 0.f;
    }
}

// kX2: per-vocab x-gate preacts, gate-interleaved f16:
// embX[v][j][gate] = (W_ih . emb[v] + b_ih + b_hh)[gate*300+j]   (row = 2432 B)
// v2: results staged in LDS (16 x 1216 f16, stride 1224 for bank spread), then
// written to embX with coalesced f16x8 stores -- the old direct write was scalar
// f16 at 8 B stride (~25% store efficiency on 24.3 MB of HBM writes).
__global__ __launch_bounds__(512, 2)
void kX2(const f16* __restrict__ embT, const f16* __restrict__ Wpk,
         const float* __restrict__ biasp, f16* __restrict__ embX) {
    __shared__ __align__(16) f16 xst[16 * XST];          // 39,168 B
    int tid = threadIdx.x;
    int v0 = blockIdx.x * 16;
    int wave = tid >> 6, lane = tid & 63;
    int c = lane & 15, q = lane >> 4;
    int gate = wave >> 1, half = wave & 1;
    int nt0 = half * 10, ntiles = half ? 9 : 10;
    const f16* wp0 = Wpk + (((size_t)(gate * 19 + nt0) * 20 + 10) * 64 + lane) * 8;
    f16x8 afr[10];
    const f16* arow = embT + (size_t)(v0 + c) * KP + q * 8;
#pragma unroll
    for (int k = 0; k < 10; ++k)
        afr[k] = *(const f16x8*)(arow + k * 32);
    f16x8 buf[10];
#pragma unroll
    for (int s = 0; s < 10; ++s)
        buf[s] = *(const f16x8*)(wp0 + (size_t)s * 512);
#pragma unroll 1
    for (int nt = 0; nt < ntiles - 1; ++nt) {
        int jcol = (nt0 + nt) * 16 + c;
        float bia = biasp[gate * GP + jcol];
        f32x4 acc = {bia, bia, bia, bia};
#pragma unroll
        for (int k = 0; k < 10; ++k) {
            acc = __builtin_amdgcn_mfma_f32_16x16x32_f16(afr[k], buf[k], acc, 0, 0, 0);
            buf[k] = *(const f16x8*)(wp0 + (size_t)(nt * 20 + k + 20) * 512);
        }
#pragma unroll
        for (int r = 0; r < 4; ++r)
            xst[(q * 4 + r) * XST + jcol * 4 + gate] = (f16)acc[r];
    }
    {
        int nt = ntiles - 1;
        int jcol = (nt0 + nt) * 16 + c;
        float bia = biasp[gate * GP + jcol];
        f32x4 acc = {bia, bia, bia, bia};
#pragma unroll
        for (int k = 0; k < 10; ++k)
            acc = __builtin_amdgcn_mfma_f32_16x16x32_f16(afr[k], buf[k], acc, 0, 0, 0);
#pragma unroll
        for (int r = 0; r < 4; ++r)
            xst[(q * 4 + r) * XST + jcol * 4 + gate] = (f16)acc[r];
    }
    __syncthreads();
    // coalesced bulk write: 16 rows x 1216 f16 = 2,432 f16x8 chunks
    for (int i = tid; i < 16 * 152; i += 512) {
        int m = i / 152, c8 = i - m * 152;
        *(f16x8*)(embX + (size_t)(v0 + m) * G4 + c8 * 8) =
            *(const f16x8*)(xst + m * XST + c8 * 8);
    }
}

// kR28: kR27 (proven 312 us recurrence) + residency REBALANCE. kR27's waves were
// imbalanced: waves 5-7 did 12 units/step (2 resident + 10 streamed) while waves
// 0-4 did 8 (1+7) -- the per-step barrier makes waves 5-7 the critical path. The
// 11-unit resident budget (112,640 B, exactly full) is redistributed to the
// critical waves: Rw = {1,1,0,0,0,3,3,3}. Critical-path streamed units 10 -> 9
// (resident ds_read ~120cyc vs streamed ~300-500cyc L2 exposure). Total streamed
// volume unchanged (65 units/step) -> FETCH invariant. t=0 peel kept. Same
// registers, same numerics (rebalance only changes WHERE weights are read from).
__global__ __launch_bounds__(512, 2)
void kR28(const int* __restrict__ cap,
          const int* __restrict__ cap_len,
          const f16* __restrict__ embX,
          const f16* __restrict__ WgS,
          const float* __restrict__ Wc,
          const float* __restrict__ cls_b,
          float* __restrict__ out) {
    extern __shared__ __align__(16) char smem[];
    f16*   hbufA = (f16*)smem;                           // 2*16*LDA*2 = 20,992 B
    float* cbuf  = (float*)(smem + 20992);               // 16*LDC*4  = 19,712 B
    int*   capv  = (int*)(smem + 40704);                 // 2,048 B
    int*   lens  = (int*)(smem + 42752);                 // 64 B
    f16*   wres  = (f16*)(smem + 43008);                 // 112,640 B  (total 155,648)
    int tid = threadIdx.x;
    int b0 = blockIdx.x * ROWS;
    if (tid < ROWS) lens[tid] = cap_len[b0 + tid];
    for (int i = tid; i < ROWS * T_SZ; i += 512) capv[i] = cap[(size_t)b0 * T_SZ + i];
    for (int i = tid; i < 2 * ROWS * LDA; i += 512) hbufA[i] = (f16)0.f;
    for (int i = tid; i < ROWS * LDC; i += 512) cbuf[i] = 0.f;

    int wave = tid >> 6, lane = tid & 63;
    int c = lane & 15, q = lane >> 4;
    int tstart = (wave < 5) ? 2 * wave : 10 + 3 * (wave - 5);   // 19 = 5x2 + 3x3
    int tcnt   = (wave < 5) ? 2 : 3;
    // resident units: {1,1,0,0,0,3,3,3} = 11 total = 112,640 B exactly
    int Rw = (wave < 2) ? 1 : (wave < 5) ? 0 : 3;
    f16* resw = wres + ((wave < 2) ? wave * 5120
                        : (wave < 5) ? 0
                        : 10240 + (wave - 5) * 15360);
    const f16* wp0 = WgS + ((size_t)(tstart * 40) * 64 + lane) * 8;
    // resident fill (once; plain loads, barrier-synchronized)
    for (int u = 0; u < Rw; ++u)
#pragma unroll
        for (int k = 0; k < 10; ++k)
            *(f16x8*)(resw + (u * 10 + k) * 512 + lane * 8) =
                *(const f16x8*)(wp0 + (size_t)(u * 10 + k) * 512);
    __syncthreads();

    int cur = 0;
    // prologue: buf holds the first STREAMED unit (tile tstart, gate Rw);
    // the wrap prefetch at each step's last streamed unit keeps it primed forever.
    f16x8 buf[10];
#pragma unroll
    for (int s = 0; s < 10; ++s)
        buf[s] = *(const f16x8*)(wp0 + (size_t)(Rw * 10 + s) * 512);

    // ---- t = 0 peeled: h == 0 -> all MFMA results exactly 0; no weight use ----
    {
        const int t = 0;
        f16* hn = hbufA + 1 * (ROWS * LDA);
#pragma unroll 1
        for (int nt = 0; nt < tcnt; ++nt) {
            int col = (tstart + nt) * 16 + c;
            f16x4 xi[4];
#pragma unroll
            for (int r = 0; r < 4; ++r) {
                int v = capv[(q * 4 + r) * T_SZ + t];
                xi[r] = *(const f16x4*)(embX + (size_t)v * G4 + col * 4);
            }
#pragma unroll
            for (int r = 0; r < 4; ++r) {
                int row = q * 4 + r;
                f16x4 xv = xi[r];
                float ii = sigmoid_f((float)xv[0]);
                float ff = sigmoid_f((float)xv[1]);
                float gt = tanh_f((float)xv[2]);
                float oo = sigmoid_f((float)xv[3]);
                int ci = row * LDC + col;
                float cn = ff * cbuf[ci] + ii * gt;
                cbuf[ci] = cn;
                float hh = oo * tanh_f(cn);
                hn[row * LDA + col] = (f16)hh;
                if (t == lens[row] - 1) {
                    float s0 = hh * Wc[col];
                    float s1 = hh * Wc[GP + col];
                    s0 += __shfl_xor(s0, 1); s1 += __shfl_xor(s1, 1);
                    s0 += __shfl_xor(s0, 2); s1 += __shfl_xor(s1, 2);
                    s0 += __shfl_xor(s0, 4); s1 += __shfl_xor(s1, 4);
                    s0 += __shfl_xor(s0, 8); s1 += __shfl_xor(s1, 8);
                    if (c == 0) {
                        if (wave == 0 && nt == 0) { s0 += cls_b[0]; s1 += cls_b[1]; }
                        atomicAdd(out + (size_t)(b0 + row) * 2 + 0, s0);
                        atomicAdd(out + (size_t)(b0 + row) * 2 + 1, s1);
                    }
                }
            }
        }
        __syncthreads();
        cur = 1;
    }

    for (int t = 1; t < T_SZ; ++t) {
        const f16* hb = hbufA + cur * (ROWS * LDA);
        f16*       hn = hbufA + (cur ^ 1) * (ROWS * LDA);
        f16x8 afr[10];
#pragma unroll
        for (int k = 0; k < 10; ++k)
            afr[k] = *(const f16x8*)(hb + c * LDA + k * 32 + q * 8);
#pragma unroll 1
        for (int nt = 0; nt < tcnt; ++nt) {
            int col = (tstart + nt) * 16 + c;
            // x-preacts: direct gather, issued here, consumed after 40 MFMAs
            f16x4 xi[4];
#pragma unroll
            for (int r = 0; r < 4; ++r) {
                int v = capv[(q * 4 + r) * T_SZ + t];
                xi[r] = *(const f16x4*)(embX + (size_t)v * G4 + col * 4);
            }
            f32x4 acc0 = {0.f, 0.f, 0.f, 0.f};
            f32x4 acc1 = {0.f, 0.f, 0.f, 0.f};
            f32x4 acc2 = {0.f, 0.f, 0.f, 0.f};
            f32x4 acc3 = {0.f, 0.f, 0.f, 0.f};
#pragma unroll
            for (int g = 0; g < 4; ++g) {
                f32x4* ag = (g == 0) ? &acc0 : (g == 1) ? &acc1 : (g == 2) ? &acc2 : &acc3;
                if (nt == 0 && g < Rw) {
                    // resident unit: frags from LDS, no global issue
                    const f16* rb = resw + g * 5120 + lane * 8;
#pragma unroll
                    for (int k = 0; k < 10; ++k)
                        *ag = __builtin_amdgcn_mfma_f32_16x16x32_f16(
                            afr[k], *(const f16x8*)(rb + k * 512), *ag, 0, 0, 0);
                } else {
                    // streamed unit: consume buf, prefetch next streamed unit
                    int nbase = (g < 3) ? (nt * 40 + (g + 1) * 10)
                              : ((nt + 1 < tcnt) ? (nt + 1) * 40 : Rw * 10);
#pragma unroll
                    for (int k = 0; k < 10; ++k) {
                        *ag = __builtin_amdgcn_mfma_f32_16x16x32_f16(
                            afr[k], buf[k], *ag, 0, 0, 0);
                        buf[k] = *(const f16x8*)(wp0 + (size_t)(nbase + k) * 512);
                    }
                }
            }
            // cell update + fused classifier
#pragma unroll
            for (int r = 0; r < 4; ++r) {
                int row = q * 4 + r;
                f16x4 xv = xi[r];
                float gi = acc0[r] + (float)xv[0];
                float gf = acc1[r] + (float)xv[1];
                float gg = acc2[r] + (float)xv[2];
                float go = acc3[r] + (float)xv[3];
                float ii = sigmoid_f(gi);
                float ff = sigmoid_f(gf);
                float gt = tanh_f(gg);
                float oo = sigmoid_f(go);
                int ci = row * LDC + col;
                float cn = ff * cbuf[ci] + ii * gt;
                cbuf[ci] = cn;
                float hh = oo * tanh_f(cn);
                hn[row * LDA + col] = (f16)hh;
                if (t == lens[row] - 1) {
                    float s0 = hh * Wc[col];
                    float s1 = hh * Wc[GP + col];
                    s0 += __shfl_xor(s0, 1); s1 += __shfl_xor(s1, 1);
                    s0 += __shfl_xor(s0, 2); s1 += __shfl_xor(s1, 2);
                    s0 += __shfl_xor(s0, 4); s1 += __shfl_xor(s1, 4);
                    s0 += __shfl_xor(s0, 8); s1 += __shfl_xor(s1, 8);
                    if (c == 0) {
                        if (wave == 0 && nt == 0) { s0 += cls_b[0]; s1 += cls_b[1]; }
                        atomicAdd(out + (size_t)(b0 + row) * 2 + 0, s0);
                        atomicAdd(out + (size_t)(b0 + row) * 2 + 1, s1);
                    }
                }
            }
        }
        __syncthreads();
        cur ^= 1;
    }
}

// kR8 (fallback, proven): fused [h|x] recurrence for small-ws runs.
__global__ __launch_bounds__(512, 2)
void kR8(const int* __restrict__ cap,
         const int* __restrict__ cap_len,
         const f16* __restrict__ embT,
         const f16* __restrict__ Wpk,
         const float* __restrict__ biasp,
         float* __restrict__ hlast) {
    extern __shared__ __align__(16) char smem[];
    f16*   hbuf  = (f16*)smem;                          // 10496
    f16*   xbuf  = (f16*)(smem + 10496);                // 10496
    f16*   gates = (f16*)(smem + 20992);                // 39168
    float* biasL = (float*)(smem + 60160);              // 4864
    int*   capv  = (int*)(smem + 65024);                // 2048
    int*   lens  = (int*)(smem + 67072);                // 64
    int tid = threadIdx.x;
    int b0 = blockIdx.x * 16;
    if (tid < 16) lens[tid] = cap_len[b0 + tid];
    for (int i = tid; i < 16 * T_SZ; i += 512) capv[i] = cap[(size_t)b0 * T_SZ + i];
    for (int i = tid; i < 16 * LDA; i += 512) hbuf[i] = (f16)0.f;
    for (int i = tid; i < G4; i += 512) biasL[i] = biasp[i];
    __syncthreads();
    for (int i = tid; i < 16 * 40; i += 512) {
        int m = i / 40, c8 = i - m * 40;
        int v = capv[m * T_SZ + 0];
        *(f16x8*)(xbuf + m * LDA + c8 * 8) = *(const f16x8*)(embT + (size_t)v * KP + c8 * 8);
    }
    __syncthreads();
    int wave = tid >> 6, lane = tid & 63;
    int c = lane & 15, q = lane >> 4;
    int gate = wave >> 1, half = wave & 1;
    int nt0 = half * 10, ntiles = half ? 9 : 10;
    const f16* wp0 = Wpk + ((size_t)((gate * 19 + nt0) * 20) * 64 + lane) * 8;
    const f16* hrow = hbuf + c * LDA + q * 8;
    const f16* xrow = xbuf + c * LDA + q * 8;
    float creg[10];
#pragma unroll
    for (int i = 0; i < 10; ++i) creg[i] = 0.f;

    for (int t = 0; t < T_SZ; ++t) {
        f16x8 afr[10];
#pragma unroll
        for (int k = 0; k < 10; ++k)
            afr[k] = *(const f16x8*)(hrow + k * 32);
        f16x8 buf[10];
#pragma unroll
        for (int s = 0; s < 10; ++s)
            buf[s] = *(const f16x8*)(wp0 + (size_t)s * 512);
#pragma unroll 1
        for (int nt = 0; nt < ntiles - 1; ++nt) {
            int base = nt * 20;
            int ncol = gate * GP + (nt0 + nt) * 16 + c;
            float bia = biasL[ncol];
            f32x4 acch = {bia, bia, bia, bia};
            f32x4 accx = {0.f, 0.f, 0.f, 0.f};
#pragma unroll
            for (int k = 0; k < 20; ++k) {
                if (k < 10) {
                    acch = __builtin_amdgcn_mfma_f32_16x16x32_f16(afr[k], buf[k % 10], acch, 0, 0, 0);
                } else {
                    f16x8 a = *(const f16x8*)(xrow + (k - 10) * 32);
                    accx = __builtin_amdgcn_mfma_f32_16x16x32_f16(a, buf[k % 10], accx, 0, 0, 0);
                }
                buf[k % 10] = *(const f16x8*)(wp0 + (size_t)(base + k + 10) * 512);
            }
#pragma unroll
            for (int r = 0; r < 4; ++r)
                gates[(q * 4 + r) * LDG + ncol] = (f16)(acch[r] + accx[r]);
        }
        {
            int nt = ntiles - 1;
            int base = nt * 20;
            int ncol = gate * GP + (nt0 + nt) * 16 + c;
            float bia = biasL[ncol];
            f32x4 acch = {bia, bia, bia, bia};
            f32x4 accx = {0.f, 0.f, 0.f, 0.f};
#pragma unroll
            for (int k = 0; k < 20; ++k) {
                if (k < 10) {
                    acch = __builtin_amdgcn_mfma_f32_16x16x32_f16(afr[k], buf[k % 10], acch, 0, 0, 0);
                    buf[k % 10] = *(const f16x8*)(wp0 + (size_t)(base + k + 10) * 512);
                } else {
                    f16x8 a = *(const f16x8*)(xrow + (k - 10) * 32);
                    accx = __builtin_amdgcn_mfma_f32_16x16x32_f16(a, buf[k % 10], accx, 0, 0, 0);
                }
            }
#pragma unroll
            for (int r = 0; r < 4; ++r)
                gates[(q * 4 + r) * LDG + ncol] = (f16)(acch[r] + accx[r]);
        }
        __syncthreads();
        int tp1 = t + 1;
        if (tp1 < T_SZ) {
            for (int i = tid; i < 16 * 40; i += 512) {
                int m = i / 40, c8 = i - m * 40;
                int v = capv[m * T_SZ + tp1];
                *(f16x8*)(xbuf + m * LDA + c8 * 8) =
                    *(const f16x8*)(embT + (size_t)v * KP + c8 * 8);
            }
        }
#pragma unroll
        for (int it = 0; it < 10; ++it) {
            int idx = tid + it * 512;
            int m = idx / 320, j = idx - m * 320;
            if (j < H_SZ) {
                const f16* gr = gates + m * LDG;
                float gi = (float)gr[j];
                float gf = (float)gr[GP + j];
                float gg = (float)gr[2 * GP + j];
                float go = (float)gr[3 * GP + j];
                float ii = sigmoid_f(gi);
                float ff = sigmoid_f(gf);
                float gt = tanh_f(gg);
                float oo = sigmoid_f(go);
                float cn = ff * creg[it] + ii * gt;
                creg[it] = cn;
                float hh = oo * tanh_f(cn);
                hbuf[m * LDA + j] = (f16)hh;
                if (t == lens[m] - 1) hlast[(size_t)(b0 + m) * GP + j] = hh;
            }
        }
        __syncthreads();
    }
}

// kC: out[row][cl] = hlast[row] . Wc[cl] + cls_b[cl]   (fallback path only)
__global__ void kC(const float* __restrict__ hlast, const float* __restrict__ Wc,
                   const float* __restrict__ cls_b, float* __restrict__ out) {
    int row = blockIdx.x, lane = threadIdx.x;
    const float* h = hlast + (size_t)row * GP;
    float s0 = 0.f, s1 = 0.f;
    for (int j = lane; j < H_SZ; j += 64) {
        float hv = h[j];
        s0 += hv * Wc[j];
        s1 += hv * Wc[GP + j];
    }
    for (int off = 32; off; off >>= 1) {
        s0 += __shfl_down(s0, off);
        s1 += __shfl_down(s1, off);
    }
    if (lane == 0) {
        out[row * 2 + 0] = s0 + cls_b[0];
        out[row * 2 + 1] = s1 + cls_b[1];
    }
}

extern "C" void kernel_launch(void* const* d_in, const int* in_sizes, int n_in,
                              void* d_out, int out_size, void* d_ws, size_t ws_size,
                              hipStream_t stream) {
    const int*   cap     = (const int*)d_in[0];
    const int*   cap_len = (const int*)d_in[1];
    const float* embed_w = (const float*)d_in[2];
    const float* W_ih    = (const float*)d_in[3];
    const float* W_hh    = (const float*)d_in[4];
    const float* b_ih    = (const float*)d_in[5];
    const float* b_hh    = (const float*)d_in[6];
    const float* cls_v   = (const float*)d_in[7];
    const float* cls_g   = (const float*)d_in[8];
    const float* cls_b   = (const float*)d_in[9];
    float* out = (float*)d_out;

    char* w = (char*)d_ws;
    size_t off = 0;
    auto alloc = [&](size_t bytes) -> void* {
        void* p = w + off;
        off += (bytes + 255) & ~(size_t)255;
        return p;
    };
    f16*   embT  = (f16*)alloc((size_t)VOCAB * KP * sizeof(f16));      // 6.4 MB
    f16*   Wpk   = (f16*)alloc((size_t)1520 * 64 * 8 * sizeof(f16));   // 1.56 MB
    f16*   WgS   = (f16*)alloc((size_t)800 * 64 * 8 * sizeof(f16));    // 819 KB
    float* biasp = (float*)alloc((size_t)G4 * sizeof(float));
    float* Wc    = (float*)alloc((size_t)2 * GP * sizeof(float));
    float* hlast = (float*)alloc((size_t)B_SZ * GP * sizeof(float));   // 5.0 MB (fallback)
    f16*   embX  = (f16*)(w + off);                                    // 24.3 MB f16 [V][GP][4]
    size_t need_split = off + ((size_t)VOCAB * GP * 4 * sizeof(f16) + 255);
    bool split = (ws_size >= need_split);          // deterministic per run

    kP0<<<VOCAB, KP, 0, stream>>>(embed_w, embT);
    kPW2<<<1520, 64, 0, stream>>>(W_ih, W_hh, b_ih, b_hh, Wpk, biasp);
    kP2<<<1, 64, 0, stream>>>(cls_v, cls_g, Wc);
    if (split) {
        (void)hipMemsetAsync(out, 0, (size_t)out_size, stream);   // fused-kC accumulator
        kPW4<<<800, 64, 0, stream>>>(W_hh, WgS);
        kX2<<<VOCAB / 16, 512, 0, stream>>>(embT, Wpk, biasp, embX);
        static const int smem_r28 = 155648;
        (void)hipFuncSetAttribute((const void*)kR28,
                                  hipFuncAttributeMaxDynamicSharedMemorySize, smem_r28);
        kR28<<<NBLK, 512, smem_r28, stream>>>(cap, cap_len, embX, WgS, Wc, cls_b, out);
    } else {
        static const int smem_r8 = 67072 + 64;
        (void)hipFuncSetAttribute((const void*)kR8,
                                  hipFuncAttributeMaxDynamicSharedMemorySize, smem_r8);
        kR8<<<B_SZ / 16, 512, smem_r8, stream>>>(cap, cap_len, embT, Wpk, biasp, hlast);
        kC<<<B_SZ, 64, 0, stream>>>(hlast, Wc, cls_b, out);
    }
}

// Round 15
// 397.572 us; speedup vs baseline: 1.0322x; 1.0322x over previous
//
#include <hip/hip_runtime.h>
#include <hip/hip_fp16.h>

typedef _Float16 f16;
typedef _Float16 f16x4 __attribute__((ext_vector_type(4)));
typedef _Float16 f16x8 __attribute__((ext_vector_type(8)));
typedef float f32x4 __attribute__((ext_vector_type(4)));

#define B_SZ   4096
#define T_SZ   32
#define VOCAB  10000
#define E_SZ   300
#define H_SZ   300
#define KP     320          // embT row width (10x32)
#define GP     304          // per-gate padded N (19x16)
#define G4     1216         // 4*GP
#define LDA    328          // hbuf row stride f16
#define LDG    1224         // kR8 gates row stride f16
#define LDC    308          // cbuf row stride f32
#define XST    1224         // kX2 LDS out row stride f16
#define ROWS   16
#define NBLK   (B_SZ/ROWS)  // 256 blocks -> 1 per CU

__device__ __forceinline__ float sigmoid_f(float x) {
    return 1.f / (1.f + __expf(-x));
}
__device__ __forceinline__ float tanh_f(float x) {
    return 2.f / (1.f + __expf(-2.f * x)) - 1.f;
}

// P0: embed_w f32 [V][300] -> embT f16 [V][320] zero-padded
__global__ void kP0(const float* __restrict__ ew, f16* __restrict__ embT) {
    int v = blockIdx.x, k = threadIdx.x;           // 320 threads
    embT[(size_t)v * KP + k] = (k < E_SZ) ? (f16)ew[(size_t)v * E_SZ + k] : (f16)0.f;
}

// kPW2: fused-stream packing (for kX2 / kR8): block (gate,nt,k20), 1 KB each.
__global__ void kPW2(const float* __restrict__ wih, const float* __restrict__ whh,
                     const float* __restrict__ bih, const float* __restrict__ bhh,
                     f16* __restrict__ Wpk, float* __restrict__ biasp) {
    int bid = blockIdx.x;                          // 0..1519 = (gate*19+nt)*20+k
    int lane = threadIdx.x;                        // 64
    int k = bid % 20, ntg = bid / 20;
    int nt = ntg % 19, gate = ntg / 19;
    int c = lane & 15, q = lane >> 4;
    int j = nt * 16 + c;
    int src = gate * H_SZ + j;
    f16 vals[8];
#pragma unroll
    for (int jj = 0; jj < 8; ++jj) {
        int kk = k * 32 + q * 8 + jj;
        float v = 0.f;
        if (j < H_SZ) {
            if (kk < KP) { if (kk < H_SZ) v = whh[(size_t)src * H_SZ + kk]; }
            else { int kx = kk - KP; if (kx < E_SZ) v = wih[(size_t)src * E_SZ + kx]; }
        }
        vals[jj] = (f16)v;
    }
    *(f16x8*)(Wpk + ((size_t)bid * 64 + lane) * 8) = *(const f16x8*)vals;
    if (k == 0 && q == 0)
        biasp[gate * GP + j] = (j < H_SZ) ? (bih[src] + bhh[src]) : 0.f;
}

// kPW4: gate-major W_hh-only packing: block (nt, gate, k10), 1 KB each.
// 800 blocks (760 real + 40 zero slack).
__global__ void kPW4(const float* __restrict__ whh, f16* __restrict__ WgS) {
    int bid = blockIdx.x;                          // 0..799
    int lane = threadIdx.x;
    int c = lane & 15, q = lane >> 4;
    f16 vals[8];
    if (bid < 760) {
        int nt = bid / 40, g = (bid % 40) / 10, k = bid % 10;
        int j = nt * 16 + c;
        int src = g * H_SZ + j;
#pragma unroll
        for (int jj = 0; jj < 8; ++jj) {
            int kk = k * 32 + q * 8 + jj;
            float v = (j < H_SZ && kk < H_SZ) ? whh[(size_t)src * H_SZ + kk] : 0.f;
            vals[jj] = (f16)v;
        }
    } else {
#pragma unroll
        for (int jj = 0; jj < 8; ++jj) vals[jj] = (f16)0.f;
    }
    *(f16x8*)(WgS + ((size_t)bid * 64 + lane) * 8) = *(const f16x8*)vals;
}

// P2: weight-normed classifier W = g * v / ||v||  -> Wc f32 [2][GP]
// cols 300..303 zeroed (fused classifier multiplies h(=0) by Wc there).
__global__ void kP2(const float* __restrict__ cls_v, const float* __restrict__ cls_g,
                    float* __restrict__ Wc) {
    int lane = threadIdx.x;
    for (int cl = 0; cl < 2; ++cl) {
        float s = 0.f;
        for (int j = lane; j < H_SZ; j += 64) { float v = cls_v[cl * H_SZ + j]; s += v * v; }
        for (int off = 32; off; off >>= 1) s += __shfl_down(s, off);
        float nrm = sqrtf(__shfl(s, 0));
        float scale = cls_g[cl] / nrm;
        for (int j = lane; j < GP; j += 64)
            Wc[cl * GP + j] = (j < H_SZ) ? cls_v[cl * H_SZ + j] * scale : 0.f;
    }
}

// kX2 v2: x-gate preacts with LDS-staged coalesced embX writes (kR28-proven:
// fixed overhead 90.2 -> 88.0 us vs scalar gate-interleaved stores).
__global__ __launch_bounds__(512, 2)
void kX2(const f16* __restrict__ embT, const f16* __restrict__ Wpk,
         const float* __restrict__ biasp, f16* __restrict__ embX) {
    __shared__ __align__(16) f16 xst[16 * XST];          // 39,168 B
    int tid = threadIdx.x;
    int v0 = blockIdx.x * 16;
    int wave = tid >> 6, lane = tid & 63;
    int c = lane & 15, q = lane >> 4;
    int gate = wave >> 1, half = wave & 1;
    int nt0 = half * 10, ntiles = half ? 9 : 10;
    const f16* wp0 = Wpk + (((size_t)(gate * 19 + nt0) * 20 + 10) * 64 + lane) * 8;
    f16x8 afr[10];
    const f16* arow = embT + (size_t)(v0 + c) * KP + q * 8;
#pragma unroll
    for (int k = 0; k < 10; ++k)
        afr[k] = *(const f16x8*)(arow + k * 32);
    f16x8 buf[10];
#pragma unroll
    for (int s = 0; s < 10; ++s)
        buf[s] = *(const f16x8*)(wp0 + (size_t)s * 512);
#pragma unroll 1
    for (int nt = 0; nt < ntiles - 1; ++nt) {
        int jcol = (nt0 + nt) * 16 + c;
        float bia = biasp[gate * GP + jcol];
        f32x4 acc = {bia, bia, bia, bia};
#pragma unroll
        for (int k = 0; k < 10; ++k) {
            acc = __builtin_amdgcn_mfma_f32_16x16x32_f16(afr[k], buf[k], acc, 0, 0, 0);
            buf[k] = *(const f16x8*)(wp0 + (size_t)(nt * 20 + k + 20) * 512);
        }
#pragma unroll
        for (int r = 0; r < 4; ++r)
            xst[(q * 4 + r) * XST + jcol * 4 + gate] = (f16)acc[r];
    }
    {
        int nt = ntiles - 1;
        int jcol = (nt0 + nt) * 16 + c;
        float bia = biasp[gate * GP + jcol];
        f32x4 acc = {bia, bia, bia, bia};
#pragma unroll
        for (int k = 0; k < 10; ++k)
            acc = __builtin_amdgcn_mfma_f32_16x16x32_f16(afr[k], buf[k], acc, 0, 0, 0);
#pragma unroll
        for (int r = 0; r < 4; ++r)
            xst[(q * 4 + r) * XST + jcol * 4 + gate] = (f16)acc[r];
    }
    __syncthreads();
    // coalesced bulk write: 16 rows x 1216 f16 = 2,432 f16x8 chunks
    for (int i = tid; i < 16 * 152; i += 512) {
        int m = i / 152, c8 = i - m * 152;
        *(f16x8*)(embX + (size_t)(v0 + m) * G4 + c8 * 8) =
            *(const f16x8*)(xst + m * XST + c8 * 8);
    }
}

// kR27: the proven champion recurrence (312.4 us, VGPR=100, zero spill):
// kR22 structure (512 thr, 16 rows/block, 11 LDS-resident units Rw={1x5,2x3},
// buf[10] rotating stream with wrap prefetch, LDS cbuf, fused classifier,
// 1 barrier/step) + t=0 peel (h==0 -> all MFMAs exactly 0; step 0 is just
// x-gather + cell update; weight pipe untouched). kR29's async-LDS staging
// crashed (vmcnt schedule polluted by uncounted VMEM ops); kR28's residency
// rebalance regressed (resident ~= streamed); deep register lookahead spills
// at the 128-VGPR wall. This is the verified optimum of the family.
__global__ __launch_bounds__(512, 2)
void kR27(const int* __restrict__ cap,
          const int* __restrict__ cap_len,
          const f16* __restrict__ embX,
          const f16* __restrict__ WgS,
          const float* __restrict__ Wc,
          const float* __restrict__ cls_b,
          float* __restrict__ out) {
    extern __shared__ __align__(16) char smem[];
    f16*   hbufA = (f16*)smem;                           // 2*16*LDA*2 = 20,992 B
    float* cbuf  = (float*)(smem + 20992);               // 16*LDC*4  = 19,712 B
    int*   capv  = (int*)(smem + 40704);                 // 2,048 B
    int*   lens  = (int*)(smem + 42752);                 // 64 B
    f16*   wres  = (f16*)(smem + 43008);                 // 112,640 B  (total 155,648)
    int tid = threadIdx.x;
    int b0 = blockIdx.x * ROWS;
    if (tid < ROWS) lens[tid] = cap_len[b0 + tid];
    for (int i = tid; i < ROWS * T_SZ; i += 512) capv[i] = cap[(size_t)b0 * T_SZ + i];
    for (int i = tid; i < 2 * ROWS * LDA; i += 512) hbufA[i] = (f16)0.f;
    for (int i = tid; i < ROWS * LDC; i += 512) cbuf[i] = 0.f;

    int wave = tid >> 6, lane = tid & 63;
    int c = lane & 15, q = lane >> 4;
    int tstart = (wave < 5) ? 2 * wave : 10 + 3 * (wave - 5);   // 19 = 5x2 + 3x3
    int tcnt   = (wave < 5) ? 2 : 3;
    int Rw     = (wave < 5) ? 1 : 2;                             // resident units (11 total)
    f16* resw = wres + ((wave < 5) ? wave * 5120 : 25600 + (wave - 5) * 10240);
    const f16* wp0 = WgS + ((size_t)(tstart * 40) * 64 + lane) * 8;
    // resident fill (once; plain loads, barrier-synchronized -> no async hazards)
    for (int u = 0; u < Rw; ++u)
#pragma unroll
        for (int k = 0; k < 10; ++k)
            *(f16x8*)(resw + (u * 10 + k) * 512 + lane * 8) =
                *(const f16x8*)(wp0 + (size_t)(u * 10 + k) * 512);
    __syncthreads();

    int cur = 0;
    // prologue: buf holds the first STREAMED unit (tile tstart, gate Rw);
    // the wrap prefetch at each step's last streamed unit keeps it primed forever.
    f16x8 buf[10];
#pragma unroll
    for (int s = 0; s < 10; ++s)
        buf[s] = *(const f16x8*)(wp0 + (size_t)(Rw * 10 + s) * 512);

    // ---- t = 0 peeled: h == 0 -> all MFMA results exactly 0; no weight use ----
    {
        const int t = 0;
        f16* hn = hbufA + 1 * (ROWS * LDA);
#pragma unroll 1
        for (int nt = 0; nt < tcnt; ++nt) {
            int col = (tstart + nt) * 16 + c;
            f16x4 xi[4];
#pragma unroll
            for (int r = 0; r < 4; ++r) {
                int v = capv[(q * 4 + r) * T_SZ + t];
                xi[r] = *(const f16x4*)(embX + (size_t)v * G4 + col * 4);
            }
#pragma unroll
            for (int r = 0; r < 4; ++r) {
                int row = q * 4 + r;
                f16x4 xv = xi[r];
                float ii = sigmoid_f((float)xv[0]);
                float ff = sigmoid_f((float)xv[1]);
                float gt = tanh_f((float)xv[2]);
                float oo = sigmoid_f((float)xv[3]);
                int ci = row * LDC + col;
                float cn = ff * cbuf[ci] + ii * gt;
                cbuf[ci] = cn;
                float hh = oo * tanh_f(cn);
                hn[row * LDA + col] = (f16)hh;
                if (t == lens[row] - 1) {
                    float s0 = hh * Wc[col];
                    float s1 = hh * Wc[GP + col];
                    s0 += __shfl_xor(s0, 1); s1 += __shfl_xor(s1, 1);
                    s0 += __shfl_xor(s0, 2); s1 += __shfl_xor(s1, 2);
                    s0 += __shfl_xor(s0, 4); s1 += __shfl_xor(s1, 4);
                    s0 += __shfl_xor(s0, 8); s1 += __shfl_xor(s1, 8);
                    if (c == 0) {
                        if (wave == 0 && nt == 0) { s0 += cls_b[0]; s1 += cls_b[1]; }
                        atomicAdd(out + (size_t)(b0 + row) * 2 + 0, s0);
                        atomicAdd(out + (size_t)(b0 + row) * 2 + 1, s1);
                    }
                }
            }
        }
        __syncthreads();
        cur = 1;
    }

    for (int t = 1; t < T_SZ; ++t) {
        const f16* hb = hbufA + cur * (ROWS * LDA);
        f16*       hn = hbufA + (cur ^ 1) * (ROWS * LDA);
        f16x8 afr[10];
#pragma unroll
        for (int k = 0; k < 10; ++k)
            afr[k] = *(const f16x8*)(hb + c * LDA + k * 32 + q * 8);
#pragma unroll 1
        for (int nt = 0; nt < tcnt; ++nt) {
            int col = (tstart + nt) * 16 + c;
            // x-preacts: direct gather, issued here, consumed after 40 MFMAs
            f16x4 xi[4];
#pragma unroll
            for (int r = 0; r < 4; ++r) {
                int v = capv[(q * 4 + r) * T_SZ + t];
                xi[r] = *(const f16x4*)(embX + (size_t)v * G4 + col * 4);
            }
            f32x4 acc0 = {0.f, 0.f, 0.f, 0.f};
            f32x4 acc1 = {0.f, 0.f, 0.f, 0.f};
            f32x4 acc2 = {0.f, 0.f, 0.f, 0.f};
            f32x4 acc3 = {0.f, 0.f, 0.f, 0.f};
#pragma unroll
            for (int g = 0; g < 4; ++g) {
                f32x4* ag = (g == 0) ? &acc0 : (g == 1) ? &acc1 : (g == 2) ? &acc2 : &acc3;
                if (nt == 0 && g < Rw) {
                    // resident unit: frags from LDS, no global issue
                    const f16* rb = resw + g * 5120 + lane * 8;
#pragma unroll
                    for (int k = 0; k < 10; ++k)
                        *ag = __builtin_amdgcn_mfma_f32_16x16x32_f16(
                            afr[k], *(const f16x8*)(rb + k * 512), *ag, 0, 0, 0);
                } else {
                    // streamed unit: consume buf, prefetch next streamed unit
                    int nbase = (g < 3) ? (nt * 40 + (g + 1) * 10)
                              : ((nt + 1 < tcnt) ? (nt + 1) * 40 : Rw * 10);
#pragma unroll
                    for (int k = 0; k < 10; ++k) {
                        *ag = __builtin_amdgcn_mfma_f32_16x16x32_f16(
                            afr[k], buf[k], *ag, 0, 0, 0);
                        buf[k] = *(const f16x8*)(wp0 + (size_t)(nbase + k) * 512);
                    }
                }
            }
            // cell update + fused classifier
#pragma unroll
            for (int r = 0; r < 4; ++r) {
                int row = q * 4 + r;
                f16x4 xv = xi[r];
                float gi = acc0[r] + (float)xv[0];
                float gf = acc1[r] + (float)xv[1];
                float gg = acc2[r] + (float)xv[2];
                float go = acc3[r] + (float)xv[3];
                float ii = sigmoid_f(gi);
                float ff = sigmoid_f(gf);
                float gt = tanh_f(gg);
                float oo = sigmoid_f(go);
                int ci = row * LDC + col;
                float cn = ff * cbuf[ci] + ii * gt;
                cbuf[ci] = cn;
                float hh = oo * tanh_f(cn);
                hn[row * LDA + col] = (f16)hh;
                if (t == lens[row] - 1) {
                    float s0 = hh * Wc[col];
                    float s1 = hh * Wc[GP + col];
                    s0 += __shfl_xor(s0, 1); s1 += __shfl_xor(s1, 1);
                    s0 += __shfl_xor(s0, 2); s1 += __shfl_xor(s1, 2);
                    s0 += __shfl_xor(s0, 4); s1 += __shfl_xor(s1, 4);
                    s0 += __shfl_xor(s0, 8); s1 += __shfl_xor(s1, 8);
                    if (c == 0) {
                        if (wave == 0 && nt == 0) { s0 += cls_b[0]; s1 += cls_b[1]; }
                        atomicAdd(out + (size_t)(b0 + row) * 2 + 0, s0);
                        atomicAdd(out + (size_t)(b0 + row) * 2 + 1, s1);
                    }
                }
            }
        }
        __syncthreads();
        cur ^= 1;
    }
}

// kR8 (fallback, proven): fused [h|x] recurrence for small-ws runs.
__global__ __launch_bounds__(512, 2)
void kR8(const int* __restrict__ cap,
         const int* __restrict__ cap_len,
         const f16* __restrict__ embT,
         const f16* __restrict__ Wpk,
         const float* __restrict__ biasp,
         float* __restrict__ hlast) {
    extern __shared__ __align__(16) char smem[];
    f16*   hbuf  = (f16*)smem;                          // 10496
    f16*   xbuf  = (f16*)(smem + 10496);                // 10496
    f16*   gates = (f16*)(smem + 20992);                // 39168
    float* biasL = (float*)(smem + 60160);              // 4864
    int*   capv  = (int*)(smem + 65024);                // 2048
    int*   lens  = (int*)(smem + 67072);                // 64
    int tid = threadIdx.x;
    int b0 = blockIdx.x * 16;
    if (tid < 16) lens[tid] = cap_len[b0 + tid];
    for (int i = tid; i < 16 * T_SZ; i += 512) capv[i] = cap[(size_t)b0 * T_SZ + i];
    for (int i = tid; i < 16 * LDA; i += 512) hbuf[i] = (f16)0.f;
    for (int i = tid; i < G4; i += 512) biasL[i] = biasp[i];
    __syncthreads();
    for (int i = tid; i < 16 * 40; i += 512) {
        int m = i / 40, c8 = i - m * 40;
        int v = capv[m * T_SZ + 0];
        *(f16x8*)(xbuf + m * LDA + c8 * 8) = *(const f16x8*)(embT + (size_t)v * KP + c8 * 8);
    }
    __syncthreads();
    int wave = tid >> 6, lane = tid & 63;
    int c = lane & 15, q = lane >> 4;
    int gate = wave >> 1, half = wave & 1;
    int nt0 = half * 10, ntiles = half ? 9 : 10;
    const f16* wp0 = Wpk + ((size_t)((gate * 19 + nt0) * 20) * 64 + lane) * 8;
    const f16* hrow = hbuf + c * LDA + q * 8;
    const f16* xrow = xbuf + c * LDA + q * 8;
    float creg[10];
#pragma unroll
    for (int i = 0; i < 10; ++i) creg[i] = 0.f;

    for (int t = 0; t < T_SZ; ++t) {
        f16x8 afr[10];
#pragma unroll
        for (int k = 0; k < 10; ++k)
            afr[k] = *(const f16x8*)(hrow + k * 32);
        f16x8 buf[10];
#pragma unroll
        for (int s = 0; s < 10; ++s)
            buf[s] = *(const f16x8*)(wp0 + (size_t)s * 512);
#pragma unroll 1
        for (int nt = 0; nt < ntiles - 1; ++nt) {
            int base = nt * 20;
            int ncol = gate * GP + (nt0 + nt) * 16 + c;
            float bia = biasL[ncol];
            f32x4 acch = {bia, bia, bia, bia};
            f32x4 accx = {0.f, 0.f, 0.f, 0.f};
#pragma unroll
            for (int k = 0; k < 20; ++k) {
                if (k < 10) {
                    acch = __builtin_amdgcn_mfma_f32_16x16x32_f16(afr[k], buf[k % 10], acch, 0, 0, 0);
                } else {
                    f16x8 a = *(const f16x8*)(xrow + (k - 10) * 32);
                    accx = __builtin_amdgcn_mfma_f32_16x16x32_f16(a, buf[k % 10], accx, 0, 0, 0);
                }
                buf[k % 10] = *(const f16x8*)(wp0 + (size_t)(base + k + 10) * 512);
            }
#pragma unroll
            for (int r = 0; r < 4; ++r)
                gates[(q * 4 + r) * LDG + ncol] = (f16)(acch[r] + accx[r]);
        }
        {
            int nt = ntiles - 1;
            int base = nt * 20;
            int ncol = gate * GP + (nt0 + nt) * 16 + c;
            float bia = biasL[ncol];
            f32x4 acch = {bia, bia, bia, bia};
            f32x4 accx = {0.f, 0.f, 0.f, 0.f};
#pragma unroll
            for (int k = 0; k < 20; ++k) {
                if (k < 10) {
                    acch = __builtin_amdgcn_mfma_f32_16x16x32_f16(afr[k], buf[k % 10], acch, 0, 0, 0);
                    buf[k % 10] = *(const f16x8*)(wp0 + (size_t)(base + k + 10) * 512);
                } else {
                    f16x8 a = *(const f16x8*)(xrow + (k - 10) * 32);
                    accx = __builtin_amdgcn_mfma_f32_16x16x32_f16(a, buf[k % 10], accx, 0, 0, 0);
                }
            }
#pragma unroll
            for (int r = 0; r < 4; ++r)
                gates[(q * 4 + r) * LDG + ncol] = (f16)(acch[r] + accx[r]);
        }
        __syncthreads();
        int tp1 = t + 1;
        if (tp1 < T_SZ) {
            for (int i = tid; i < 16 * 40; i += 512) {
                int m = i / 40, c8 = i - m * 40;
                int v = capv[m * T_SZ + tp1];
                *(f16x8*)(xbuf + m * LDA + c8 * 8) =
                    *(const f16x8*)(embT + (size_t)v * KP + c8 * 8);
            }
        }
#pragma unroll
        for (int it = 0; it < 10; ++it) {
            int idx = tid + it * 512;
            int m = idx / 320, j = idx - m * 320;
            if (j < H_SZ) {
                const f16* gr = gates + m * LDG;
                float gi = (float)gr[j];
                float gf = (float)gr[GP + j];
                float gg = (float)gr[2 * GP + j];
                float go = (float)gr[3 * GP + j];
                float ii = sigmoid_f(gi);
                float ff = sigmoid_f(gf);
                float gt = tanh_f(gg);
                float oo = sigmoid_f(go);
                float cn = ff * creg[it] + ii * gt;
                creg[it] = cn;
                float hh = oo * tanh_f(cn);
                hbuf[m * LDA + j] = (f16)hh;
                if (t == lens[m] - 1) hlast[(size_t)(b0 + m) * GP + j] = hh;
            }
        }
        __syncthreads();
    }
}

// kC: out[row][cl] = hlast[row] . Wc[cl] + cls_b[cl]   (fallback path only)
__global__ void kC(const float* __restrict__ hlast, const float* __restrict__ Wc,
                   const float* __restrict__ cls_b, float* __restrict__ out) {
    int row = blockIdx.x, lane = threadIdx.x;
    const float* h = hlast + (size_t)row * GP;
    float s0 = 0.f, s1 = 0.f;
    for (int j = lane; j < H_SZ; j += 64) {
        float hv = h[j];
        s0 += hv * Wc[j];
        s1 += hv * Wc[GP + j];
    }
    for (int off = 32; off; off >>= 1) {
        s0 += __shfl_down(s0, off);
        s1 += __shfl_down(s1, off);
    }
    if (lane == 0) {
        out[row * 2 + 0] = s0 + cls_b[0];
        out[row * 2 + 1] = s1 + cls_b[1];
    }
}

extern "C" void kernel_launch(void* const* d_in, const int* in_sizes, int n_in,
                              void* d_out, int out_size, void* d_ws, size_t ws_size,
                              hipStream_t stream) {
    const int*   cap     = (const int*)d_in[0];
    const int*   cap_len = (const int*)d_in[1];
    const float* embed_w = (const float*)d_in[2];
    const float* W_ih    = (const float*)d_in[3];
    const float* W_hh    = (const float*)d_in[4];
    const float* b_ih    = (const float*)d_in[5];
    const float* b_hh    = (const float*)d_in[6];
    const float* cls_v   = (const float*)d_in[7];
    const float* cls_g   = (const float*)d_in[8];
    const float* cls_b   = (const float*)d_in[9];
    float* out = (float*)d_out;

    char* w = (char*)d_ws;
    size_t off = 0;
    auto alloc = [&](size_t bytes) -> void* {
        void* p = w + off;
        off += (bytes + 255) & ~(size_t)255;
        return p;
    };
    f16*   embT  = (f16*)alloc((size_t)VOCAB * KP * sizeof(f16));      // 6.4 MB
    f16*   Wpk   = (f16*)alloc((size_t)1520 * 64 * 8 * sizeof(f16));   // 1.56 MB
    f16*   WgS   = (f16*)alloc((size_t)800 * 64 * 8 * sizeof(f16));    // 819 KB
    float* biasp = (float*)alloc((size_t)G4 * sizeof(float));
    float* Wc    = (float*)alloc((size_t)2 * GP * sizeof(float));
    float* hlast = (float*)alloc((size_t)B_SZ * GP * sizeof(float));   // 5.0 MB (fallback)
    f16*   embX  = (f16*)(w + off);                                    // 24.3 MB f16 [V][GP][4]
    size_t need_split = off + ((size_t)VOCAB * GP * 4 * sizeof(f16) + 255);
    bool split = (ws_size >= need_split);          // deterministic per run

    kP0<<<VOCAB, KP, 0, stream>>>(embed_w, embT);
    kPW2<<<1520, 64, 0, stream>>>(W_ih, W_hh, b_ih, b_hh, Wpk, biasp);
    kP2<<<1, 64, 0, stream>>>(cls_v, cls_g, Wc);
    if (split) {
        (void)hipMemsetAsync(out, 0, (size_t)out_size, stream);   // fused-kC accumulator
        kPW4<<<800, 64, 0, stream>>>(W_hh, WgS);
        kX2<<<VOCAB / 16, 512, 0, stream>>>(embT, Wpk, biasp, embX);
        static const int smem_r27 = 155648;
        (void)hipFuncSetAttribute((const void*)kR27,
                                  hipFuncAttributeMaxDynamicSharedMemorySize, smem_r27);
        kR27<<<NBLK, 512, smem_r27, stream>>>(cap, cap_len, embX, WgS, Wc, cls_b, out);
    } else {
        static const int smem_r8 = 67072 + 64;
        (void)hipFuncSetAttribute((const void*)kR8,
                                  hipFuncAttributeMaxDynamicSharedMemorySize, smem_r8);
        kR8<<<B_SZ / 16, 512, smem_r8, stream>>>(cap, cap_len, embT, Wpk, biasp, hlast);
        kC<<<B_SZ, 64, 0, stream>>>(hlast, Wc, cls_b, out);
    }
}